// Round 3
// baseline (187.931 us; speedup 1.0000x reference)
//
#include <hip/hip_runtime.h>
#include <hip/hip_bf16.h>

#define DEV static __device__ __forceinline__

typedef __attribute__((ext_vector_type(8))) short bf16x8;
typedef __attribute__((ext_vector_type(4))) short bf16x4;
typedef __attribute__((ext_vector_type(4))) float f32x4;

#define MFMA16(a, b, c) __builtin_amdgcn_mfma_f32_16x16x32_bf16((a), (b), (c), 0, 0, 0)

// 16x16x16 bf16 MFMA: C-layout of a previous MFMA == this op's B-fragment layout,
// which lets S^T (post-softmax) feed PV^T with zero cross-lane movement.
DEV f32x4 pv_mfma(bf16x4 a, bf16x4 b, f32x4 c) {
#if __has_builtin(__builtin_amdgcn_mfma_f32_16x16x16_bf16)
  return __builtin_amdgcn_mfma_f32_16x16x16_bf16(a, b, c, 0, 0, 0);
#elif __has_builtin(__builtin_amdgcn_mfma_f32_16x16x16bf16_1k)
  return __builtin_amdgcn_mfma_f32_16x16x16bf16_1k(a, b, c, 0, 0, 0);
#else
  f32x4 d;
  asm volatile("v_mfma_f32_16x16x16_bf16 %0, %1, %2, %3"
               : "=v"(d) : "v"(a), "v"(b), "v"(c));
  return d;
#endif
}

#define B_ 2
#define T_ 2048
#define D_ 1024
#define H_ 16
#define HD_ 64
#define LOG2E 1.4426950408889634f

DEV short f2bf(float f) {
  union { float f; unsigned u; } w; w.f = f;
  unsigned u = w.u + 0x7fffu + ((w.u >> 16) & 1u);
  return (short)(u >> 16);
}

// ---------------- RoPE cos/sin table
__global__ void rope_table_k(float2* __restrict__ tab) {
  int i = blockIdx.x * 256 + threadIdx.x;
  if (i >= T_ * 32) return;
  int t = i >> 5, d = i & 31;
  float theta = powf(10000.0f, -(float)(2 * d) / 64.0f);
  float a = (float)t * theta;
  tab[i] = make_float2(cosf(a), sinf(a));
}

// ---------------- GEMM tile params
#define BM 128
#define BN 128
#define BK 32
#define LDA_ 40

// ---------------- K1: qkv = x @ w_attn^T, fused RoPE, writes Q (pre-scaled by
// log2e/8), K, and V transposed [bh][hd][t].
__global__ void gemm_qkv_k(const float* __restrict__ X, const float* __restrict__ W,
                           short* __restrict__ Q, short* __restrict__ Ko,
                           short* __restrict__ Vt, const float2* __restrict__ tab) {
  __shared__ short aLds[BM * LDA_];
  __shared__ short bLds[BN * LDA_];
  const int tid = threadIdx.x;
  const int lane = tid & 63, wid = tid >> 6;
  const int wr = wid >> 1, wc = wid & 1;
  const int l15 = lane & 15, lg = lane >> 4;
  const int mBase = blockIdx.y * BM, nBase = blockIdx.x * BN;
  const int sRow = tid >> 3, sC4 = tid & 7;

  float4 ra[4], rb[4];
  auto loadT = [&](const float* __restrict__ P, int base, int kt, float4* r) {
#pragma unroll
    for (int p = 0; p < 4; ++p)
      r[p] = *(const float4*)&P[(size_t)(base + sRow + p * 32) * 1024 + kt * BK + sC4 * 4];
  };
  auto storeT = [&](short* lds, float4* r) {
#pragma unroll
    for (int p = 0; p < 4; ++p) {
      short4 s4;
      s4.x = f2bf(r[p].x); s4.y = f2bf(r[p].y);
      s4.z = f2bf(r[p].z); s4.w = f2bf(r[p].w);
      *(short4*)&lds[(sRow + p * 32) * LDA_ + sC4 * 4] = s4;
    }
  };

  f32x4 acc[4][4];
#pragma unroll
  for (int i = 0; i < 4; ++i)
#pragma unroll
    for (int j = 0; j < 4; ++j) acc[i][j] = (f32x4){0.f, 0.f, 0.f, 0.f};

  loadT(X, mBase, 0, ra);
  loadT(W, nBase, 0, rb);

  for (int kt = 0; kt < 1024 / BK; ++kt) {
    storeT(aLds, ra);
    storeT(bLds, rb);
    __syncthreads();
    if (kt + 1 < 1024 / BK) { loadT(X, mBase, kt + 1, ra); loadT(W, nBase, kt + 1, rb); }
    bf16x8 af[4], bfv[4];
#pragma unroll
    for (int i = 0; i < 4; ++i) {
      af[i]  = *(const bf16x8*)&aLds[(wr * 64 + i * 16 + l15) * LDA_ + lg * 8];
      bfv[i] = *(const bf16x8*)&bLds[(wc * 64 + i * 16 + l15) * LDA_ + lg * 8];
    }
#pragma unroll
    for (int mi = 0; mi < 4; ++mi)
#pragma unroll
      for (int ni = 0; ni < 4; ++ni)
        acc[mi][ni] = MFMA16(af[mi], bfv[ni], acc[mi][ni]);
    __syncthreads();
  }

  const int sec = nBase >> 10;
#pragma unroll
  for (int mi = 0; mi < 4; ++mi) {
    const int m0 = mBase + wr * 64 + mi * 16 + lg * 4;
#pragma unroll
    for (int ni = 0; ni < 4; ++ni) {
      const int n = nBase + wc * 64 + ni * 16 + l15;
      const int hd = n & 63;
      const int h = (n >> 6) & 15;
      if (sec < 2) {
        short* dst = (sec == 0) ? Q : Ko;
        const float qscale = (sec == 0) ? (0.125f * LOG2E) : 1.0f;
#pragma unroll
        for (int r = 0; r < 4; ++r) {
          int m = m0 + r; int b = m >> 11; int t = m & 2047;
          float v = acc[mi][ni][r];
          float pv = __shfl_xor(v, 1);
          float2 cs = tab[t * 32 + (hd >> 1)];
          float o = (lane & 1) ? (v * cs.x + pv * cs.y) : (v * cs.x - pv * cs.y);
          o *= qscale;
          dst[(((size_t)b * H_ + h) * T_ + t) * HD_ + hd] = f2bf(o);
        }
      } else {
        int b = m0 >> 11; int t0 = m0 & 2047;
        short4 s4;
        s4.x = f2bf(acc[mi][ni][0]); s4.y = f2bf(acc[mi][ni][1]);
        s4.z = f2bf(acc[mi][ni][2]); s4.w = f2bf(acc[mi][ni][3]);
        *(short4*)&Vt[(((size_t)b * H_ + h) * HD_ + hd) * T_ + t0] = s4;
      }
    }
  }
}

// ---------------- K2: flash attention, anti-window mask, swapped-operand chain.
// S^T = mfma(K, Q) -> per-lane exp2 -> bf16 pack -> directly the B-frag of
// O^T = mfma16x16x16(V^T, P^T). No P LDS round-trip. KVBLK=128.
#define KVB 128
#define KSTR 72    // kLds row stride (shorts); cols XOR-swizzled by (row&7) in 8-short units
#define VSTR 140   // vLds row stride (shorts): 70 dw/row -> bank step 6 -> ~2-way (free)

__global__ void attn_k(const short* __restrict__ Qg, const short* __restrict__ Kg,
                       const short* __restrict__ Vg, short* __restrict__ Y) {
  __shared__ short kLds[KVB * KSTR];
  __shared__ short vLds[HD_ * VSTR];
  const int tid = threadIdx.x;
  const int lane = tid & 63, w = tid >> 6;
  const int l15 = lane & 15, lg = lane >> 4;
  // XCD-aware swizzle (1024 % 8 == 0): each XCD owns 4 whole heads.
  const int bid = blockIdx.x;
  const int wg = ((bid & 7) << 7) | (bid >> 3);
  const int qt = wg & 31, bh = wg >> 5;
  const int b = bh >> 4, h = bh & 15;
  const int q0 = qt * 64;
  const short* Qh = Qg + (size_t)bh * T_ * HD_;
  const short* Kh = Kg + (size_t)bh * T_ * HD_;
  const short* Vh = Vg + (size_t)bh * HD_ * T_;

  // Q as B-fragment (hoisted): B[hd][q], q = l15-indexed row
  bf16x8 qb[2];
  {
    const int qrow = q0 + w * 16 + l15;
    qb[0] = *(const bf16x8*)&Qh[(size_t)qrow * HD_ + lg * 8];
    qb[1] = *(const bf16x8*)&Qh[(size_t)qrow * HD_ + 32 + lg * 8];
  }
  const int i_q = q0 + w * 16 + l15;   // this lane's query row (constant)
  const bool iok = (i_q >= 16);
  const int jlo = i_q - 128, jhi = i_q + 128;

  f32x4 ot[4];
#pragma unroll
  for (int i = 0; i < 4; ++i) ot[i] = (f32x4){0.f, 0.f, 0.f, 0.f};
  float lsum = 0.f;

  // staging indices
  const int kRow = tid >> 3, kC8 = tid & 7;       // K: 128 rows x 64 shorts
  const int vRow = tid >> 4, vC = (tid & 15) * 8; // V: 64 rows x 128 shorts

  bf16x8 kreg[4], vreg[4];
  auto issueLoad = [&](int k0) {
#pragma unroll
    for (int p = 0; p < 4; ++p)
      kreg[p] = *(const bf16x8*)&Kh[(size_t)(k0 + kRow + p * 32) * HD_ + kC8 * 8];
#pragma unroll
    for (int p = 0; p < 4; ++p)
      vreg[p] = *(const bf16x8*)&Vh[(size_t)(vRow + p * 16) * T_ + k0 + vC];
  };
  auto skip128 = [&](int kt) {
    const int k0 = kt * KVB;
    const int ilo = (q0 > 16) ? q0 : 16;
    const int jl = (k0 > 16) ? k0 : 16;
    return (k0 + 127 <= ilo + 128) && (q0 + 63 <= jl + 128);
  };

  const int NT = T_ / KVB;
  int kt = 0;
  while (skip128(kt)) ++kt;
  issueLoad(kt * KVB);

  while (kt < NT) {
    int ktn = kt + 1;
    while (ktn < NT && skip128(ktn)) ++ktn;

    __syncthreads();  // all waves done reading LDS from previous tile
#pragma unroll
    for (int p = 0; p < 4; ++p) {
      const int row = kRow + p * 32;
      *(bf16x8*)&kLds[row * KSTR + ((kC8 ^ (row & 7)) * 8)] = kreg[p];
    }
#pragma unroll
    for (int p = 0; p < 4; ++p) {
      const int row = vRow + p * 16;
      bf16x4 lo = {vreg[p][0], vreg[p][1], vreg[p][2], vreg[p][3]};
      bf16x4 hi = {vreg[p][4], vreg[p][5], vreg[p][6], vreg[p][7]};
      *(bf16x4*)&vLds[row * VSTR + vC] = lo;
      *(bf16x4*)&vLds[row * VSTR + vC + 4] = hi;
    }
    if (ktn < NT) issueLoad(ktn * KVB);  // in flight across barrier, lands under compute
    asm volatile("s_waitcnt lgkmcnt(0)" ::: "memory");
    __builtin_amdgcn_s_barrier();

    const int k0 = kt * KVB;
#pragma unroll
    for (int hv = 0; hv < 2; ++hv) {
      const int kh = k0 + hv * 64;
      const bool clean = (q0 >= 16) && (kh >= 16) &&
                         ((kh + 63 < q0 - 128) || (kh > q0 + 63 + 128));
      // QK^T (swapped): S^T[k][q]
      f32x4 s[4];
#pragma unroll
      for (int i = 0; i < 4; ++i) s[i] = (f32x4){0.f, 0.f, 0.f, 0.f};
      __builtin_amdgcn_s_setprio(1);
#pragma unroll
      for (int nf = 0; nf < 4; ++nf)
#pragma unroll
        for (int ks = 0; ks < 2; ++ks) {
          const int row = hv * 64 + nf * 16 + l15;
          bf16x8 ka = *(const bf16x8*)&kLds[row * KSTR + (((ks * 4 + lg) ^ (l15 & 7)) * 8)];
          s[nf] = MFMA16(ka, qb[ks], s[nf]);
        }
      __builtin_amdgcn_s_setprio(0);
      // V^T fragments (issued before exp so LDS latency hides under VALU)
      bf16x4 va[4][4];
#pragma unroll
      for (int dt = 0; dt < 4; ++dt)
#pragma unroll
        for (int kk = 0; kk < 4; ++kk)
          va[dt][kk] = *(const bf16x4*)&vLds[(dt * 16 + l15) * VSTR + hv * 64 + kk * 16 + lg * 4];
      // mask + exp2 + pack (k-index is lane-local: j = kh + nf*16 + lg*4 + r)
      bf16x4 pf[4];
#pragma unroll
      for (int nf = 0; nf < 4; ++nf) {
#pragma unroll
        for (int r = 0; r < 4; ++r) {
          if (!clean) {
            const int j = kh + nf * 16 + lg * 4 + r;
            const bool keep = iok && (j >= 16) && ((j < jlo) || (j > jhi));
            if (!keep) s[nf][r] = -__builtin_inff();
          }
          float e = __builtin_amdgcn_exp2f(s[nf][r]);
          lsum += e;
          pf[nf][r] = f2bf(e);
        }
      }
      // PV^T: O^T[d][q] += V^T-frag x P^T-frag
      __builtin_amdgcn_s_setprio(1);
#pragma unroll
      for (int kk = 0; kk < 4; ++kk)
#pragma unroll
        for (int dt = 0; dt < 4; ++dt)
          ot[dt] = pv_mfma(va[dt][kk], pf[kk], ot[dt]);
      __builtin_amdgcn_s_setprio(0);
    }
    kt = ktn;
  }

  // row-sum: lane holds partial over its k-slots; q lives at l15 across lg groups
  float l = lsum;
  l += __shfl_xor(l, 16);
  l += __shfl_xor(l, 32);
  const float rl = 1.0f / fmaxf(l, 1e-20f);
  const int t = q0 + w * 16 + l15;
#pragma unroll
  for (int dt = 0; dt < 4; ++dt) {
    short4 s4;
    s4.x = f2bf(ot[dt][0] * rl);
    s4.y = f2bf(ot[dt][1] * rl);
    s4.z = f2bf(ot[dt][2] * rl);
    s4.w = f2bf(ot[dt][3] * rl);
    *(short4*)&Y[((size_t)(b * T_ + t)) * D_ + h * HD_ + dt * 16 + lg * 4] = s4;
  }
}

// ---------------- K3: out = y @ w_proj^T
__global__ void gemm_proj_k(const short* __restrict__ Yg, const float* __restrict__ W,
                            float* __restrict__ Out) {
  __shared__ short aLds[BM * LDA_];
  __shared__ short bLds[BN * LDA_];
  const int tid = threadIdx.x;
  const int lane = tid & 63, wid = tid >> 6;
  const int wr = wid >> 1, wc = wid & 1;
  const int l15 = lane & 15, lg = lane >> 4;
  const int mBase = blockIdx.y * BM, nBase = blockIdx.x * BN;
  const int aRow = tid >> 2, aC = (tid & 3) * 8;
  const int sRow = tid >> 3, sC4 = tid & 7;

  bf16x8 ra[2];
  float4 rb[4];
  auto loadA = [&](int kt) {
#pragma unroll
    for (int p = 0; p < 2; ++p)
      ra[p] = *(const bf16x8*)&Yg[(size_t)(mBase + aRow + p * 64) * 1024 + kt * BK + aC];
  };
  auto loadB = [&](int kt) {
#pragma unroll
    for (int p = 0; p < 4; ++p)
      rb[p] = *(const float4*)&W[(size_t)(nBase + sRow + p * 32) * 1024 + kt * BK + sC4 * 4];
  };

  f32x4 acc[4][4];
#pragma unroll
  for (int i = 0; i < 4; ++i)
#pragma unroll
    for (int j = 0; j < 4; ++j) acc[i][j] = (f32x4){0.f, 0.f, 0.f, 0.f};

  loadA(0);
  loadB(0);
  for (int kt = 0; kt < 1024 / BK; ++kt) {
#pragma unroll
    for (int p = 0; p < 2; ++p)
      *(bf16x8*)&aLds[(aRow + p * 64) * LDA_ + aC] = ra[p];
#pragma unroll
    for (int p = 0; p < 4; ++p) {
      short4 s4;
      s4.x = f2bf(rb[p].x); s4.y = f2bf(rb[p].y);
      s4.z = f2bf(rb[p].z); s4.w = f2bf(rb[p].w);
      *(short4*)&bLds[(sRow + p * 32) * LDA_ + sC4 * 4] = s4;
    }
    __syncthreads();
    if (kt + 1 < 1024 / BK) { loadA(kt + 1); loadB(kt + 1); }
    bf16x8 af[4], bfv[4];
#pragma unroll
    for (int i = 0; i < 4; ++i) {
      af[i]  = *(const bf16x8*)&aLds[(wr * 64 + i * 16 + l15) * LDA_ + lg * 8];
      bfv[i] = *(const bf16x8*)&bLds[(wc * 64 + i * 16 + l15) * LDA_ + lg * 8];
    }
#pragma unroll
    for (int mi = 0; mi < 4; ++mi)
#pragma unroll
      for (int ni = 0; ni < 4; ++ni)
        acc[mi][ni] = MFMA16(af[mi], bfv[ni], acc[mi][ni]);
    __syncthreads();
  }

#pragma unroll
  for (int mi = 0; mi < 4; ++mi)
#pragma unroll
    for (int ni = 0; ni < 4; ++ni)
#pragma unroll
      for (int r = 0; r < 4; ++r)
        Out[(size_t)(mBase + wr * 64 + mi * 16 + lg * 4 + r) * 1024 +
            nBase + wc * 64 + ni * 16 + l15] = acc[mi][ni][r];
}

extern "C" void kernel_launch(void* const* d_in, const int* in_sizes, int n_in,
                              void* d_out, int out_size, void* d_ws, size_t ws_size,
                              hipStream_t stream) {
  const float* x = (const float*)d_in[0];
  const float* w_attn = (const float*)d_in[1];
  const float* w_proj = (const float*)d_in[2];
  float* out = (float*)d_out;
  char* ws = (char*)d_ws;
  short* Q  = (short*)(ws);
  short* K  = (short*)(ws + (size_t)8388608);
  short* Vt = (short*)(ws + (size_t)16777216);
  short* Y  = (short*)(ws + (size_t)25165824);
  float2* tab = (float2*)(ws + (size_t)33554432);

  rope_table_k<<<dim3((T_ * 32 + 255) / 256), dim3(256), 0, stream>>>(tab);
  gemm_qkv_k<<<dim3(24, 32), dim3(256), 0, stream>>>(x, w_attn, Q, K, Vt, tab);
  attn_k<<<dim3(B_ * H_ * (T_ / 64)), dim3(256), 0, stream>>>(Q, K, Vt, Y);
  gemm_proj_k<<<dim3(8, 32), dim3(256), 0, stream>>>(Y, w_proj, out);
}

// Round 4
// 187.629 us; speedup vs baseline: 1.0016x; 1.0016x over previous
//
#include <hip/hip_runtime.h>
#include <hip/hip_bf16.h>

#define DEV static __device__ __forceinline__

typedef __attribute__((ext_vector_type(8))) short bf16x8;
typedef __attribute__((ext_vector_type(4))) short bf16x4;
typedef __attribute__((ext_vector_type(4))) float f32x4;

#define MFMA16(a, b, c) __builtin_amdgcn_mfma_f32_16x16x32_bf16((a), (b), (c), 0, 0, 0)

// 16x16x16 bf16 MFMA: C-layout of a previous MFMA == this op's B-fragment layout,
// which lets S^T (post-softmax) feed PV^T with zero cross-lane movement.
DEV f32x4 pv_mfma(bf16x4 a, bf16x4 b, f32x4 c) {
#if __has_builtin(__builtin_amdgcn_mfma_f32_16x16x16_bf16)
  return __builtin_amdgcn_mfma_f32_16x16x16_bf16(a, b, c, 0, 0, 0);
#elif __has_builtin(__builtin_amdgcn_mfma_f32_16x16x16bf16_1k)
  return __builtin_amdgcn_mfma_f32_16x16x16bf16_1k(a, b, c, 0, 0, 0);
#else
  f32x4 d;
  asm volatile("v_mfma_f32_16x16x16_bf16 %0, %1, %2, %3"
               : "=v"(d) : "v"(a), "v"(b), "v"(c));
  return d;
#endif
}

#define B_ 2
#define T_ 2048
#define D_ 1024
#define H_ 16
#define HD_ 64
#define LOG2E 1.4426950408889634f

DEV short f2bf(float f) {
  union { float f; unsigned u; } w; w.f = f;
  unsigned u = w.u + 0x7fffu + ((w.u >> 16) & 1u);
  return (short)(u >> 16);
}

// ---------------- RoPE cos/sin table
__global__ void rope_table_k(float2* __restrict__ tab) {
  int i = blockIdx.x * 256 + threadIdx.x;
  if (i >= T_ * 32) return;
  int t = i >> 5, d = i & 31;
  float theta = powf(10000.0f, -(float)(2 * d) / 64.0f);
  float a = (float)t * theta;
  tab[i] = make_float2(cosf(a), sinf(a));
}

// ---------------- GEMM tile params
#define BM 128
#define BN 128
#define BK 32
#define LDA_ 40

// ---------------- K1: qkv = x @ w_attn^T, fused RoPE, writes Q (pre-scaled by
// log2e/8), K, and V transposed [bh][hd][t].
__global__ void gemm_qkv_k(const float* __restrict__ X, const float* __restrict__ W,
                           short* __restrict__ Q, short* __restrict__ Ko,
                           short* __restrict__ Vt, const float2* __restrict__ tab) {
  __shared__ short aLds[BM * LDA_];
  __shared__ short bLds[BN * LDA_];
  const int tid = threadIdx.x;
  const int lane = tid & 63, wid = tid >> 6;
  const int wr = wid >> 1, wc = wid & 1;
  const int l15 = lane & 15, lg = lane >> 4;
  const int mBase = blockIdx.y * BM, nBase = blockIdx.x * BN;
  const int sRow = tid >> 3, sC4 = tid & 7;

  float4 ra[4], rb[4];
  auto loadT = [&](const float* __restrict__ P, int base, int kt, float4* r) {
#pragma unroll
    for (int p = 0; p < 4; ++p)
      r[p] = *(const float4*)&P[(size_t)(base + sRow + p * 32) * 1024 + kt * BK + sC4 * 4];
  };
  auto storeT = [&](short* lds, float4* r) {
#pragma unroll
    for (int p = 0; p < 4; ++p) {
      short4 s4;
      s4.x = f2bf(r[p].x); s4.y = f2bf(r[p].y);
      s4.z = f2bf(r[p].z); s4.w = f2bf(r[p].w);
      *(short4*)&lds[(sRow + p * 32) * LDA_ + sC4 * 4] = s4;
    }
  };

  f32x4 acc[4][4];
#pragma unroll
  for (int i = 0; i < 4; ++i)
#pragma unroll
    for (int j = 0; j < 4; ++j) acc[i][j] = (f32x4){0.f, 0.f, 0.f, 0.f};

  loadT(X, mBase, 0, ra);
  loadT(W, nBase, 0, rb);

  for (int kt = 0; kt < 1024 / BK; ++kt) {
    storeT(aLds, ra);
    storeT(bLds, rb);
    __syncthreads();
    if (kt + 1 < 1024 / BK) { loadT(X, mBase, kt + 1, ra); loadT(W, nBase, kt + 1, rb); }
    bf16x8 af[4], bfv[4];
#pragma unroll
    for (int i = 0; i < 4; ++i) {
      af[i]  = *(const bf16x8*)&aLds[(wr * 64 + i * 16 + l15) * LDA_ + lg * 8];
      bfv[i] = *(const bf16x8*)&bLds[(wc * 64 + i * 16 + l15) * LDA_ + lg * 8];
    }
#pragma unroll
    for (int mi = 0; mi < 4; ++mi)
#pragma unroll
      for (int ni = 0; ni < 4; ++ni)
        acc[mi][ni] = MFMA16(af[mi], bfv[ni], acc[mi][ni]);
    __syncthreads();
  }

  const int sec = nBase >> 10;
#pragma unroll
  for (int mi = 0; mi < 4; ++mi) {
    const int m0 = mBase + wr * 64 + mi * 16 + lg * 4;
#pragma unroll
    for (int ni = 0; ni < 4; ++ni) {
      const int n = nBase + wc * 64 + ni * 16 + l15;
      const int hd = n & 63;
      const int h = (n >> 6) & 15;
      if (sec < 2) {
        short* dst = (sec == 0) ? Q : Ko;
        const float qscale = (sec == 0) ? (0.125f * LOG2E) : 1.0f;
#pragma unroll
        for (int r = 0; r < 4; ++r) {
          int m = m0 + r; int b = m >> 11; int t = m & 2047;
          float v = acc[mi][ni][r];
          float pv = __shfl_xor(v, 1);
          float2 cs = tab[t * 32 + (hd >> 1)];
          float o = (lane & 1) ? (v * cs.x + pv * cs.y) : (v * cs.x - pv * cs.y);
          o *= qscale;
          dst[(((size_t)b * H_ + h) * T_ + t) * HD_ + hd] = f2bf(o);
        }
      } else {
        int b = m0 >> 11; int t0 = m0 & 2047;
        short4 s4;
        s4.x = f2bf(acc[mi][ni][0]); s4.y = f2bf(acc[mi][ni][1]);
        s4.z = f2bf(acc[mi][ni][2]); s4.w = f2bf(acc[mi][ni][3]);
        *(short4*)&Vt[(((size_t)b * H_ + h) * HD_ + hd) * T_ + t0] = s4;
      }
    }
  }
}

// ---------------- K2: flash attention, anti-window mask, swapped-operand chain.
// S^T = mfma(K, Q) -> per-lane exp2 -> bf16 pack -> directly the B-frag of
// O^T = mfma16x16x16(V^T, P^T). No P LDS round-trip. KVBLK=128.
// Epilogue: wave-local LDS transpose of O^T so the global Y store is
// full-cacheline coalesced (R2's 8B/lane @ 2KB-stride store caused ~12x
// write amplification, WRITE_SIZE 98MB).
#define KVB 128
#define KSTR 72    // kLds row stride (shorts); cols XOR-swizzled by (row&7) in 8-short units
#define VSTR 140   // vLds row stride (shorts): 70 dw/row -> bank step 6 -> ~2-way (free)
#define TSTR 72    // transpose slice row stride (16B-aligned for b128 readback)

__global__ void attn_k(const short* __restrict__ Qg, const short* __restrict__ Kg,
                       const short* __restrict__ Vg, short* __restrict__ Y) {
  __shared__ short kLds[KVB * KSTR];
  __shared__ short vLds[HD_ * VSTR];
  const int tid = threadIdx.x;
  const int lane = tid & 63, w = tid >> 6;
  const int l15 = lane & 15, lg = lane >> 4;
  // XCD-aware swizzle (1024 % 8 == 0): each XCD owns 4 whole heads.
  const int bid = blockIdx.x;
  const int wg = ((bid & 7) << 7) | (bid >> 3);
  const int qt = wg & 31, bh = wg >> 5;
  const int b = bh >> 4, h = bh & 15;
  const int q0 = qt * 64;
  const short* Qh = Qg + (size_t)bh * T_ * HD_;
  const short* Kh = Kg + (size_t)bh * T_ * HD_;
  const short* Vh = Vg + (size_t)bh * HD_ * T_;

  // Q as B-fragment (hoisted): B[hd][q], q = l15-indexed row
  bf16x8 qb[2];
  {
    const int qrow = q0 + w * 16 + l15;
    qb[0] = *(const bf16x8*)&Qh[(size_t)qrow * HD_ + lg * 8];
    qb[1] = *(const bf16x8*)&Qh[(size_t)qrow * HD_ + 32 + lg * 8];
  }
  const int i_q = q0 + w * 16 + l15;   // this lane's query row (constant)
  const bool iok = (i_q >= 16);
  const int jlo = i_q - 128, jhi = i_q + 128;

  f32x4 ot[4];
#pragma unroll
  for (int i = 0; i < 4; ++i) ot[i] = (f32x4){0.f, 0.f, 0.f, 0.f};
  float lsum = 0.f;

  // staging indices
  const int kRow = tid >> 3, kC8 = tid & 7;       // K: 128 rows x 64 shorts
  const int vRow = tid >> 4, vC = (tid & 15) * 8; // V: 64 rows x 128 shorts

  bf16x8 kreg[4], vreg[4];
  auto issueLoad = [&](int k0) {
#pragma unroll
    for (int p = 0; p < 4; ++p)
      kreg[p] = *(const bf16x8*)&Kh[(size_t)(k0 + kRow + p * 32) * HD_ + kC8 * 8];
#pragma unroll
    for (int p = 0; p < 4; ++p)
      vreg[p] = *(const bf16x8*)&Vh[(size_t)(vRow + p * 16) * T_ + k0 + vC];
  };
  auto skip128 = [&](int kt) {
    const int k0 = kt * KVB;
    const int ilo = (q0 > 16) ? q0 : 16;
    const int jl = (k0 > 16) ? k0 : 16;
    return (k0 + 127 <= ilo + 128) && (q0 + 63 <= jl + 128);
  };

  const int NT = T_ / KVB;
  int kt = 0;
  while (skip128(kt)) ++kt;
  issueLoad(kt * KVB);

  while (kt < NT) {
    int ktn = kt + 1;
    while (ktn < NT && skip128(ktn)) ++ktn;

    __syncthreads();  // all waves done reading LDS from previous tile
#pragma unroll
    for (int p = 0; p < 4; ++p) {
      const int row = kRow + p * 32;
      *(bf16x8*)&kLds[row * KSTR + ((kC8 ^ (row & 7)) * 8)] = kreg[p];
    }
#pragma unroll
    for (int p = 0; p < 4; ++p) {
      const int row = vRow + p * 16;
      bf16x4 lo = {vreg[p][0], vreg[p][1], vreg[p][2], vreg[p][3]};
      bf16x4 hi = {vreg[p][4], vreg[p][5], vreg[p][6], vreg[p][7]};
      *(bf16x4*)&vLds[row * VSTR + vC] = lo;
      *(bf16x4*)&vLds[row * VSTR + vC + 4] = hi;
    }
    if (ktn < NT) issueLoad(ktn * KVB);  // in flight across barrier, lands under compute
    asm volatile("s_waitcnt lgkmcnt(0)" ::: "memory");
    __builtin_amdgcn_s_barrier();

    const int k0 = kt * KVB;
#pragma unroll
    for (int hv = 0; hv < 2; ++hv) {
      const int kh = k0 + hv * 64;
      const bool clean = (q0 >= 16) && (kh >= 16) &&
                         ((kh + 63 < q0 - 128) || (kh > q0 + 63 + 128));
      // QK^T (swapped): S^T[k][q]
      f32x4 s[4];
#pragma unroll
      for (int i = 0; i < 4; ++i) s[i] = (f32x4){0.f, 0.f, 0.f, 0.f};
      __builtin_amdgcn_s_setprio(1);
#pragma unroll
      for (int nf = 0; nf < 4; ++nf)
#pragma unroll
        for (int ks = 0; ks < 2; ++ks) {
          const int row = hv * 64 + nf * 16 + l15;
          bf16x8 ka = *(const bf16x8*)&kLds[row * KSTR + (((ks * 4 + lg) ^ (l15 & 7)) * 8)];
          s[nf] = MFMA16(ka, qb[ks], s[nf]);
        }
      __builtin_amdgcn_s_setprio(0);
      // V^T fragments (issued before exp so LDS latency hides under VALU)
      bf16x4 va[4][4];
#pragma unroll
      for (int dt = 0; dt < 4; ++dt)
#pragma unroll
        for (int kk = 0; kk < 4; ++kk)
          va[dt][kk] = *(const bf16x4*)&vLds[(dt * 16 + l15) * VSTR + hv * 64 + kk * 16 + lg * 4];
      // mask + exp2 + pack (k-index is lane-local: j = kh + nf*16 + lg*4 + r)
      bf16x4 pf[4];
#pragma unroll
      for (int nf = 0; nf < 4; ++nf) {
#pragma unroll
        for (int r = 0; r < 4; ++r) {
          if (!clean) {
            const int j = kh + nf * 16 + lg * 4 + r;
            const bool keep = iok && (j >= 16) && ((j < jlo) || (j > jhi));
            if (!keep) s[nf][r] = -__builtin_inff();
          }
          float e = __builtin_amdgcn_exp2f(s[nf][r]);
          lsum += e;
          pf[nf][r] = f2bf(e);
        }
      }
      // PV^T: O^T[d][q] += V^T-frag x P^T-frag
      __builtin_amdgcn_s_setprio(1);
#pragma unroll
      for (int kk = 0; kk < 4; ++kk)
#pragma unroll
        for (int dt = 0; dt < 4; ++dt)
          ot[dt] = pv_mfma(va[dt][kk], pf[kk], ot[dt]);
      __builtin_amdgcn_s_setprio(0);
    }
    kt = ktn;
  }

  // row-sum: lane holds partial over its k-slots; q lives at l15 across lg groups
  float l = lsum;
  l += __shfl_xor(l, 16);
  l += __shfl_xor(l, 32);
  const float rl = 1.0f / fmaxf(l, 1e-20f);

  // ---- coalesced Y store via wave-local LDS transpose (reuse kLds) ----
  __syncthreads();  // other waves may still be reading kLds/vLds of the last tile
  short* tl = kLds + w * (16 * TSTR);  // 4 waves * 16*72 shorts = 4608 <= 9216
#pragma unroll
  for (int dt = 0; dt < 4; ++dt) {
    short4 s4;
    s4.x = f2bf(ot[dt][0] * rl);
    s4.y = f2bf(ot[dt][1] * rl);
    s4.z = f2bf(ot[dt][2] * rl);
    s4.w = f2bf(ot[dt][3] * rl);
    *(short4*)&tl[l15 * TSTR + dt * 16 + lg * 4] = s4;  // LDS[q][d]
  }
  const int rr = lane >> 3, cc = (lane & 7) * 8;
#pragma unroll
  for (int hf = 0; hf < 2; ++hf) {
    const int row = hf * 8 + rr;
    bf16x8 v = *(const bf16x8*)&tl[row * TSTR + cc];
    const int t = q0 + w * 16 + row;
    *(bf16x8*)&Y[((size_t)(b * T_ + t)) * D_ + h * HD_ + cc] = v;  // 128B/row segments
  }
}

// ---------------- K3: out = y @ w_proj^T
__global__ void gemm_proj_k(const short* __restrict__ Yg, const float* __restrict__ W,
                            float* __restrict__ Out) {
  __shared__ short aLds[BM * LDA_];
  __shared__ short bLds[BN * LDA_];
  const int tid = threadIdx.x;
  const int lane = tid & 63, wid = tid >> 6;
  const int wr = wid >> 1, wc = wid & 1;
  const int l15 = lane & 15, lg = lane >> 4;
  const int mBase = blockIdx.y * BM, nBase = blockIdx.x * BN;
  const int aRow = tid >> 2, aC = (tid & 3) * 8;
  const int sRow = tid >> 3, sC4 = tid & 7;

  bf16x8 ra[2];
  float4 rb[4];
  auto loadA = [&](int kt) {
#pragma unroll
    for (int p = 0; p < 2; ++p)
      ra[p] = *(const bf16x8*)&Yg[(size_t)(mBase + aRow + p * 64) * 1024 + kt * BK + aC];
  };
  auto loadB = [&](int kt) {
#pragma unroll
    for (int p = 0; p < 4; ++p)
      rb[p] = *(const float4*)&W[(size_t)(nBase + sRow + p * 32) * 1024 + kt * BK + sC4 * 4];
  };

  f32x4 acc[4][4];
#pragma unroll
  for (int i = 0; i < 4; ++i)
#pragma unroll
    for (int j = 0; j < 4; ++j) acc[i][j] = (f32x4){0.f, 0.f, 0.f, 0.f};

  loadA(0);
  loadB(0);
  for (int kt = 0; kt < 1024 / BK; ++kt) {
#pragma unroll
    for (int p = 0; p < 2; ++p)
      *(bf16x8*)&aLds[(aRow + p * 64) * LDA_ + aC] = ra[p];
#pragma unroll
    for (int p = 0; p < 4; ++p) {
      short4 s4;
      s4.x = f2bf(rb[p].x); s4.y = f2bf(rb[p].y);
      s4.z = f2bf(rb[p].z); s4.w = f2bf(rb[p].w);
      *(short4*)&bLds[(sRow + p * 32) * LDA_ + sC4 * 4] = s4;
    }
    __syncthreads();
    if (kt + 1 < 1024 / BK) { loadA(kt + 1); loadB(kt + 1); }
    bf16x8 af[4], bfv[4];
#pragma unroll
    for (int i = 0; i < 4; ++i) {
      af[i]  = *(const bf16x8*)&aLds[(wr * 64 + i * 16 + l15) * LDA_ + lg * 8];
      bfv[i] = *(const bf16x8*)&bLds[(wc * 64 + i * 16 + l15) * LDA_ + lg * 8];
    }
#pragma unroll
    for (int mi = 0; mi < 4; ++mi)
#pragma unroll
      for (int ni = 0; ni < 4; ++ni)
        acc[mi][ni] = MFMA16(af[mi], bfv[ni], acc[mi][ni]);
    __syncthreads();
  }

#pragma unroll
  for (int mi = 0; mi < 4; ++mi)
#pragma unroll
    for (int ni = 0; ni < 4; ++ni)
#pragma unroll
      for (int r = 0; r < 4; ++r)
        Out[(size_t)(mBase + wr * 64 + mi * 16 + lg * 4 + r) * 1024 +
            nBase + wc * 64 + ni * 16 + l15] = acc[mi][ni][r];
}

extern "C" void kernel_launch(void* const* d_in, const int* in_sizes, int n_in,
                              void* d_out, int out_size, void* d_ws, size_t ws_size,
                              hipStream_t stream) {
  const float* x = (const float*)d_in[0];
  const float* w_attn = (const float*)d_in[1];
  const float* w_proj = (const float*)d_in[2];
  float* out = (float*)d_out;
  char* ws = (char*)d_ws;
  short* Q  = (short*)(ws);
  short* K  = (short*)(ws + (size_t)8388608);
  short* Vt = (short*)(ws + (size_t)16777216);
  short* Y  = (short*)(ws + (size_t)25165824);
  float2* tab = (float2*)(ws + (size_t)33554432);

  rope_table_k<<<dim3((T_ * 32 + 255) / 256), dim3(256), 0, stream>>>(tab);
  gemm_qkv_k<<<dim3(24, 32), dim3(256), 0, stream>>>(x, w_attn, Q, K, Vt, tab);
  attn_k<<<dim3(B_ * H_ * (T_ / 64)), dim3(256), 0, stream>>>(Q, K, Vt, Y);
  gemm_proj_k<<<dim3(8, 32), dim3(256), 0, stream>>>(Y, w_proj, out);
}

// Round 6
// 144.500 us; speedup vs baseline: 1.3006x; 1.2985x over previous
//
#include <hip/hip_runtime.h>
#include <hip/hip_bf16.h>

#define DEV static __device__ __forceinline__

typedef __attribute__((ext_vector_type(8))) short bf16x8;
typedef __attribute__((ext_vector_type(4))) float f32x4;

#define MFMA16(a, b, c) __builtin_amdgcn_mfma_f32_16x16x32_bf16((a), (b), (c), 0, 0, 0)

#define B_ 2
#define T_ 2048
#define D_ 1024
#define H_ 16
#define HD_ 64
#define LOG2E 1.4426950408889634f

DEV short f2bf(float f) {
  union { float f; unsigned u; } w; w.f = f;
  unsigned u = w.u + 0x7fffu + ((w.u >> 16) & 1u);
  return (short)(u >> 16);
}

// global -> LDS direct staging, 16B per lane: lane i writes LDS at l + i*16.
DEV void gld16(const void* g, void* l) {
  __builtin_amdgcn_global_load_lds(
      (const __attribute__((address_space(1))) void*)g,
      (__attribute__((address_space(3))) void*)l, 16, 0, 0);
}

// ---------------- convert x / w_attn / w_proj fp32 -> bf16 (one launch)
#define XN 4194304   // 4096*1024
#define WAN 3145728  // 3072*1024
__global__ void cvt_k(const float* __restrict__ x, const float* __restrict__ wa,
                      const float* __restrict__ wp, short* __restrict__ xb,
                      short* __restrict__ wab, short* __restrict__ wpb) {
  size_t gi = ((size_t)blockIdx.x * 256 + threadIdx.x) * 8;
  const float* src; short* dst;
  if (gi < XN) { src = x + gi; dst = xb + gi; }
  else if (gi < XN + WAN) { src = wa + (gi - XN); dst = wab + (gi - XN); }
  else { src = wp + (gi - XN - WAN); dst = wpb + (gi - XN - WAN); }
  float4 a = *(const float4*)src;
  float4 b = *(const float4*)(src + 4);
  bf16x8 o;
  o[0] = f2bf(a.x); o[1] = f2bf(a.y); o[2] = f2bf(a.z); o[3] = f2bf(a.w);
  o[4] = f2bf(b.x); o[5] = f2bf(b.y); o[6] = f2bf(b.z); o[7] = f2bf(b.w);
  *(bf16x8*)dst = o;
}

// ---------------- RoPE cos/sin table
__global__ void rope_table_k(float2* __restrict__ tab) {
  int i = blockIdx.x * 256 + threadIdx.x;
  if (i >= T_ * 32) return;
  int t = i >> 5, d = i & 31;
  float theta = powf(10000.0f, -(float)(2 * d) / 64.0f);
  float a = (float)t * theta;
  tab[i] = make_float2(cosf(a), sinf(a));
}

// ---------------- m97-style bf16 GEMM core: 128x128 tile, BK=64, 4 waves.
// Staging: 4 gld16 calls per operand per K-step (R4 bug: only 1 -> 3/4 of the
// tile was garbage). Each call stages 8 rows (64 lanes x 16B). Since w*32 and
// p*8 are both 0 mod 8, row&7 == lane>>3, so the inverse-swizzle chunk
// gch = (lane&7)^(lane>>3) is constant across p. LDS holds chunk c^(row&7) at
// (row, c); reads xor by (row&7) to recover linear chunks (rule 21: swizzle on
// source AND read, linear LDS dest).
#define GEMM_CORE(Aptr, Bptr, KDIM)                                              \
  __shared__ short aT[128 * 64];                                                 \
  __shared__ short bT[128 * 64];                                                 \
  const int tid = threadIdx.x;                                                   \
  const int lane = tid & 63, w = tid >> 6;                                       \
  const int l15 = lane & 15, lg = lane >> 4;                                     \
  const int wr = w >> 1, wc = w & 1;                                             \
  const int mBase = blockIdx.y * 128, nBase = blockIdx.x * 128;                  \
  const int lrow = lane >> 3;                                                    \
  const int gch = (lane & 7) ^ lrow;                                             \
  const short* Asrc = (Aptr) + (size_t)(mBase + w * 32 + lrow) * (KDIM) + gch * 8;\
  const short* Bsrc = (Bptr) + (size_t)(nBase + w * 32 + lrow) * (KDIM) + gch * 8;\
  short* aDst = aT + w * 2048;                                                   \
  short* bDst = bT + w * 2048;                                                   \
  f32x4 acc[4][4];                                                               \
  _Pragma("unroll") for (int i = 0; i < 4; ++i)                                  \
  _Pragma("unroll") for (int j = 0; j < 4; ++j)                                  \
      acc[i][j] = (f32x4){0.f, 0.f, 0.f, 0.f};                                   \
  const int nk = (KDIM) / 64;                                                    \
  for (int kt = 0; kt < nk; ++kt) {                                              \
    if (kt) __syncthreads();                                                     \
    _Pragma("unroll") for (int p = 0; p < 4; ++p) {                              \
      gld16(Asrc + kt * 64 + p * 8 * (KDIM), aDst + p * 512);                    \
      gld16(Bsrc + kt * 64 + p * 8 * (KDIM), bDst + p * 512);                    \
    }                                                                            \
    __syncthreads(); /* compiler drains vmcnt(0) before barrier */               \
    bf16x8 af[4][2], bfv[4][2];                                                  \
    _Pragma("unroll") for (int i = 0; i < 4; ++i)                                \
    _Pragma("unroll") for (int s = 0; s < 2; ++s) {                              \
      const int ra = wr * 64 + i * 16 + l15;                                     \
      const int rb = wc * 64 + i * 16 + l15;                                     \
      af[i][s] = *(const bf16x8*)&aT[ra * 64 + (((4 * s + lg) ^ (ra & 7)) * 8)]; \
      bfv[i][s] = *(const bf16x8*)&bT[rb * 64 + (((4 * s + lg) ^ (rb & 7)) * 8)];\
    }                                                                            \
    _Pragma("unroll") for (int mi = 0; mi < 4; ++mi)                             \
    _Pragma("unroll") for (int ni = 0; ni < 4; ++ni)                             \
    _Pragma("unroll") for (int s = 0; s < 2; ++s)                                \
        acc[mi][ni] = MFMA16(af[mi][s], bfv[ni][s], acc[mi][ni]);                \
  }

// ---------------- K1: qkv = x @ w_attn^T (bf16 inputs), fused RoPE epilogue.
// Q pre-scaled by log2e/8; K ropes; V stored transposed [bh][hd][t].
__global__ void gemm_qkv_k(const short* __restrict__ Xb, const short* __restrict__ Wb,
                           short* __restrict__ Q, short* __restrict__ Ko,
                           short* __restrict__ Vt, const float2* __restrict__ tab) {
  GEMM_CORE(Xb, Wb, 1024)

  const int sec = nBase >> 10;
#pragma unroll
  for (int mi = 0; mi < 4; ++mi) {
    const int m0 = mBase + wr * 64 + mi * 16 + lg * 4;
#pragma unroll
    for (int ni = 0; ni < 4; ++ni) {
      const int n = nBase + wc * 64 + ni * 16 + l15;
      const int hd = n & 63;
      const int h = (n >> 6) & 15;
      if (sec < 2) {
        short* dst = (sec == 0) ? Q : Ko;
        const float qscale = (sec == 0) ? (0.125f * LOG2E) : 1.0f;
#pragma unroll
        for (int r = 0; r < 4; ++r) {
          int m = m0 + r; int b = m >> 11; int t = m & 2047;
          float v = acc[mi][ni][r];
          float pv = __shfl_xor(v, 1);  // rope pair partner (adjacent lane)
          float2 cs = tab[t * 32 + (hd >> 1)];
          float o = (lane & 1) ? (v * cs.x + pv * cs.y) : (v * cs.x - pv * cs.y);
          o *= qscale;
          dst[(((size_t)b * H_ + h) * T_ + t) * HD_ + hd] = f2bf(o);
        }
      } else {
        int b = m0 >> 11; int t0 = m0 & 2047;
        short4 s4;
        s4.x = f2bf(acc[mi][ni][0]); s4.y = f2bf(acc[mi][ni][1]);
        s4.z = f2bf(acc[mi][ni][2]); s4.w = f2bf(acc[mi][ni][3]);
        *(short4*)&Vt[(((size_t)b * H_ + h) * HD_ + hd) * T_ + t0] = s4;
      }
    }
  }
}

// ---------------- K2: flash attention (R1-proven version: 90.6us, WRITE 8.2MB)
// keep(i,j) = i>=16 && j>=16 && (j <= i-129 || j >= i+129); no-max softmax
// (|s| small, shift-invariant); Q pre-scaled so e = 2^s.
__global__ void attn_k(const short* __restrict__ Qg, const short* __restrict__ Kg,
                       const short* __restrict__ Vg, short* __restrict__ Y) {
  __shared__ short kLds[64 * 72];
  __shared__ short vLds[64 * 72];
  __shared__ short pLds[64 * 72];
  const int tid = threadIdx.x;
  const int lane = tid & 63, w = tid >> 6;
  const int l15 = lane & 15, lg = lane >> 4;
  const int bid = blockIdx.x;
  const int wg = ((bid & 7) << 7) | (bid >> 3);  // XCD swizzle: 4 heads/XCD
  const int qt = wg & 31, bh = wg >> 5;
  const int b = bh >> 4, h = bh & 15;
  const int q0 = qt * 64;
  const short* Qh = Qg + (size_t)bh * T_ * HD_;
  const short* Kh = Kg + (size_t)bh * T_ * HD_;
  const short* Vh = Vg + (size_t)bh * HD_ * T_;

  bf16x8 qa[2];
  {
    const int qrow = q0 + w * 16 + l15;
    qa[0] = *(const bf16x8*)&Qh[(size_t)qrow * HD_ + lg * 8];
    qa[1] = *(const bf16x8*)&Qh[(size_t)qrow * HD_ + 32 + lg * 8];
  }
  f32x4 o[4];
#pragma unroll
  for (int i = 0; i < 4; ++i) o[i] = (f32x4){0.f, 0.f, 0.f, 0.f};
  float lsum[4] = {0.f, 0.f, 0.f, 0.f};

  const int sRow = tid >> 3, sC = (tid & 7) * 8;
  bf16x8 kreg[2], vreg[2];
  auto issueLoad = [&](int kt) {
    const int k0 = kt * 64;
#pragma unroll
    for (int p = 0; p < 2; ++p) {
      const int row = sRow + p * 32;
      kreg[p] = *(const bf16x8*)&Kh[(size_t)(k0 + row) * HD_ + sC];
      vreg[p] = *(const bf16x8*)&Vh[(size_t)row * T_ + k0 + sC];
    }
  };
  auto inBand = [&](int kt) { const int k0 = kt * 64; return k0 >= q0 - 65 && k0 <= q0 + 65; };

  const int NT = T_ / 64;
  int kt = 0;
  while (kt < NT && inBand(kt)) ++kt;
  issueLoad(kt);

  while (kt < NT) {
    int ktn = kt + 1;
    while (ktn < NT && inBand(ktn)) ++ktn;

    __syncthreads();
#pragma unroll
    for (int p = 0; p < 2; ++p) {
      *(bf16x8*)&kLds[(sRow + p * 32) * 72 + sC] = kreg[p];
      *(bf16x8*)&vLds[(sRow + p * 32) * 72 + sC] = vreg[p];
    }
    if (ktn < NT) issueLoad(ktn);  // T14: flies under compute, across the barrier
    asm volatile("s_waitcnt lgkmcnt(0)" ::: "memory");
    __builtin_amdgcn_s_barrier();

    const int k0 = kt * 64;
    const bool clean = (q0 >= 16) && (k0 >= 16) &&
                       ((k0 + 63 < q0 - 128) || (k0 > q0 + 63 + 128));

    f32x4 s[4];
#pragma unroll
    for (int i = 0; i < 4; ++i) s[i] = (f32x4){0.f, 0.f, 0.f, 0.f};
#pragma unroll
    for (int nf = 0; nf < 4; ++nf)
#pragma unroll
      for (int ks = 0; ks < 2; ++ks) {
        bf16x8 kb = *(const bf16x8*)&kLds[(nf * 16 + l15) * 72 + ks * 32 + lg * 8];
        s[nf] = MFMA16(qa[ks], kb, s[nf]);
      }

    if (!clean) {
#pragma unroll
      for (int nf = 0; nf < 4; ++nf) {
        const int j = k0 + nf * 16 + l15;
#pragma unroll
        for (int r = 0; r < 4; ++r) {
          const int i = q0 + w * 16 + lg * 4 + r;
          const bool keep = (i >= 16) && (j >= 16) && ((j < i - 128) || (j > i + 128));
          if (!keep) s[nf][r] = -__builtin_inff();
        }
      }
    }

#pragma unroll
    for (int nf = 0; nf < 4; ++nf)
#pragma unroll
      for (int r = 0; r < 4; ++r) {
        float e = __builtin_amdgcn_exp2f(s[nf][r]);
        lsum[r] += e;
        pLds[(w * 16 + lg * 4 + r) * 72 + nf * 16 + l15] = f2bf(e);
      }
#pragma unroll
    for (int nf = 0; nf < 4; ++nf)
#pragma unroll
      for (int ks = 0; ks < 2; ++ks) {
        bf16x8 pa = *(const bf16x8*)&pLds[(w * 16 + l15) * 72 + ks * 32 + lg * 8];
        bf16x8 vb = *(const bf16x8*)&vLds[(nf * 16 + l15) * 72 + ks * 32 + lg * 8];
        o[nf] = MFMA16(pa, vb, o[nf]);
      }
    kt = ktn;
  }

  float rl[4];
#pragma unroll
  for (int r = 0; r < 4; ++r) {
    float v = lsum[r];
    v += __shfl_xor(v, 1);
    v += __shfl_xor(v, 2);
    v += __shfl_xor(v, 4);
    v += __shfl_xor(v, 8);
    rl[r] = 1.0f / fmaxf(v, 1e-20f);
  }
#pragma unroll
  for (int nf = 0; nf < 4; ++nf)
#pragma unroll
    for (int r = 0; r < 4; ++r) {
      const int t = q0 + w * 16 + lg * 4 + r;
      Y[((size_t)(b * T_ + t)) * D_ + h * HD_ + nf * 16 + l15] = f2bf(o[nf][r] * rl[r]);
    }
}

// ---------------- K3: out = y @ w_proj^T (bf16 x bf16 -> fp32)
__global__ void gemm_proj_k(const short* __restrict__ Yg, const short* __restrict__ Wb,
                            float* __restrict__ Out) {
  GEMM_CORE(Yg, Wb, 1024)

#pragma unroll
  for (int mi = 0; mi < 4; ++mi)
#pragma unroll
    for (int ni = 0; ni < 4; ++ni)
#pragma unroll
      for (int r = 0; r < 4; ++r)
        Out[(size_t)(mBase + wr * 64 + mi * 16 + lg * 4 + r) * 1024 +
            nBase + wc * 64 + ni * 16 + l15] = acc[mi][ni][r];
}

extern "C" void kernel_launch(void* const* d_in, const int* in_sizes, int n_in,
                              void* d_out, int out_size, void* d_ws, size_t ws_size,
                              hipStream_t stream) {
  const float* x = (const float*)d_in[0];
  const float* w_attn = (const float*)d_in[1];
  const float* w_proj = (const float*)d_in[2];
  float* out = (float*)d_out;
  char* ws = (char*)d_ws;
  char* outc = (char*)d_out;
  // ws: Q 8MB | K 8MB | Vt 8MB | Y 8MB | Wpb 2MB   (~34MB)
  short* Q   = (short*)(ws);
  short* K   = (short*)(ws + (size_t)8388608);
  short* Vt  = (short*)(ws + (size_t)16777216);
  short* Y   = (short*)(ws + (size_t)25165824);
  short* Wpb = (short*)(ws + (size_t)33554432);
  // d_out (16.8MB) doubles as scratch for data dead before gemm_proj writes it:
  // Xb 8MB | Wab 6MB | tab 0.5MB
  short* Xb   = (short*)(outc);
  short* Wab  = (short*)(outc + (size_t)8388608);
  float2* tab = (float2*)(outc + (size_t)14680064);

  cvt_k<<<dim3(4096), dim3(256), 0, stream>>>(x, w_attn, w_proj, Xb, Wab, Wpb);
  rope_table_k<<<dim3(256), dim3(256), 0, stream>>>(tab);
  gemm_qkv_k<<<dim3(24, 32), dim3(256), 0, stream>>>(Xb, Wab, Q, K, Vt, tab);
  attn_k<<<dim3(B_ * H_ * (T_ / 64)), dim3(256), 0, stream>>>(Q, K, Vt, Y);
  gemm_proj_k<<<dim3(8, 32), dim3(256), 0, stream>>>(Y, Wpb, out);
}